// Round 2
// baseline (309.947 us; speedup 1.0000x reference)
//
#include <hip/hip_runtime.h>
#include <cstdint>
#include <cstddef>

#define DIM    512
#define HEADS  8
#define DHEAD  64
#define NSEQ   256
#define BATCH  64
#define NROWS  (BATCH * NSEQ)   // 16384
#define HB     (HEADS * BATCH)  // 512

typedef unsigned short u16;
typedef __bf16 bf16x8 __attribute__((ext_vector_type(8)));
typedef float  f32x4  __attribute__((ext_vector_type(4)));

__device__ __forceinline__ float sigmoidf_(float x) { return 1.0f / (1.0f + expf(-x)); }

__device__ __forceinline__ u16 f2bf(float f) {
    union { float f; unsigned u; } a; a.f = f;
    return (u16)((a.u + 0x7fffu + ((a.u >> 16) & 1u)) >> 16);   // RNE
}

__device__ __forceinline__ void gload16(const void* g, void* l) {
    __builtin_amdgcn_global_load_lds((const __attribute__((address_space(1))) void*)g,
                                     (__attribute__((address_space(3))) void*)l, 16, 0, 0);
}

// ---------------------------------------------------------------------------
// Kernel 1: weight transposes + gamma-fold + LN-correction vectors.
// z=0: WT0 = (diag(gamma) @ W_in)^T, plus cs[j]=sum_i g_i W_in[i,j],
//      bW[j]=sum_i beta_i W_in[i,j] (partial colsums via atomicAdd).
// z=1: WT1 = W_out^T (unchanged).
// ---------------------------------------------------------------------------
__global__ __launch_bounds__(256)
void transpose_cast_kernel(const float* __restrict__ W0, const float* __restrict__ W1,
                           const float* __restrict__ gam, const float* __restrict__ bet,
                           u16* __restrict__ WT, float* __restrict__ cs,
                           float* __restrict__ bW)
{
    __shared__ float tile[64][65];
    const int t = threadIdx.x;
    const int bx = blockIdx.x * 64, by = blockIdx.y * 64;
    const int z = blockIdx.z;
    const float* W = z ? W1 : W0;
    u16* dst = WT + (size_t)z * 512 * 512;
#pragma unroll
    for (int i = 0; i < 16; ++i) {
        int idx = i * 256 + t, r = idx >> 6, c = idx & 63;
        tile[r][c] = W[(size_t)(by + r) * DIM + bx + c];
    }
    __syncthreads();
#pragma unroll
    for (int i = 0; i < 16; ++i) {
        int idx = i * 256 + t, r = idx >> 6, c = idx & 63;
        float wv = tile[c][r];
        if (!z) wv *= gam[by + c];
        dst[(size_t)(bx + r) * DIM + by + c] = f2bf(wv);
    }
    if (!z && t < 64) {
        float s1 = 0.f, s2 = 0.f;
#pragma unroll 8
        for (int r = 0; r < 64; ++r) {
            float wv = tile[r][t];
            s1 += gam[by + r] * wv;
            s2 += bet[by + r] * wv;
        }
        atomicAdd(cs + bx + t, s1);
        atomicAdd(bW + bx + t, s2);
    }
}

// ---------------------------------------------------------------------------
// Kernel 2: fused LN + input GEMM, v2.
//  - A reg-staged (T14): global fp32 -> VGPR for k-step t+1 issued at top of
//    iter t; cvt->bf16 + swizzled ds_write at bottom. LN stats accumulated
//    from the in-flight registers (free).
//  - Double-buffered Abuf/Bbuf (32 KB) -> ONE barrier per k-step; stage
//    latency hides under ds_read+MFMA of the current step.
//  - A LDS XOR-swizzle (chunk16 ^= (row>>1)&3) -> conflict-free A frag reads.
//  - LN applied as epilogue correction F = rstd*(acc - mu*cs) + bW.
// ---------------------------------------------------------------------------
__global__ __launch_bounds__(256)
void in_gemm_kernel(const float* __restrict__ Xq, const float* __restrict__ Xk,
                    const float* __restrict__ Xv, const u16* __restrict__ BT,
                    const float* __restrict__ cs, const float* __restrict__ bW,
                    u16* __restrict__ FT, u16* __restrict__ Fseq)
{
    // u16 layout: Abuf0 [0,4096) | Abuf1 [4096,8192) | Bbuf0 [8192,12288) |
    //             Bbuf1 [12288,16384);  union Ct [0,17408)
    __shared__ __align__(16) u16 shm[17408];
    __shared__ float muL[128], rsL[128];
    u16* Ct = shm;
    const int t = threadIdx.x, lane = t & 63, w = t >> 6;
    const int wr = w >> 1, wc = w & 1;
    // XCD-aware remap: 4 col-blocks of one row-tile share an XCD L2
    const int flat = blockIdx.y * 4 + blockIdx.x;
    const int rt = (flat & 7) * 48 + ((flat >> 3) >> 2);   // 0..383
    const int c0 = ((flat >> 3) & 3) * 128;
    const int r0 = rt * 128;
    const int cl = lane & 15, q = lane >> 4;
    const int tns = r0 >> 14, lr0 = r0 & 16383;
    const float* X = (tns == 0) ? Xq : (tns == 1) ? Xk : Xv;

    // stager mapping: thread t owns fp32 chunk sc=t&7 of rows srow[i]
    const int sc = t & 7;
    int srow[4];
#pragma unroll
    for (int i = 0; i < 4; ++i) srow[i] = (i * 256 + t) >> 3;

    f32x4 acc[4][4];
#pragma unroll
    for (int i = 0; i < 4; ++i)
#pragma unroll
        for (int j = 0; j < 4; ++j) acc[i][j] = (f32x4){0.f, 0.f, 0.f, 0.f};
    float s1[4] = {0.f, 0.f, 0.f, 0.f}, s2[4] = {0.f, 0.f, 0.f, 0.f};

    float4 nA[4];
    // ---- prologue: A(k=0) -> regs, B(k=0) -> Bbuf0, write A0 -> Abuf0
#pragma unroll
    for (int i = 0; i < 4; ++i)
        nA[i] = *(const float4*)(X + (size_t)(lr0 + srow[i]) * DIM + sc * 4);
#pragma unroll
    for (int i = 0; i < 2; ++i) {
        int idx = i * 256 + t, row = idx >> 2, ch = idx & 3;
        gload16(BT + (size_t)(c0 + row) * DIM + ch * 8, shm + 8192 + idx * 8);
    }
#pragma unroll
    for (int i = 0; i < 4; ++i) {
        float4 f = nA[i];
        s1[i] += (f.x + f.y) + (f.z + f.w);
        s2[i] += f.x * f.x + f.y * f.y + f.z * f.z + f.w * f.w;
        int row = srow[i];
        int off = row * 32 + (((((sc >> 1) ^ ((row >> 1) & 3)) << 1) | (sc & 1)) << 2);
        union { __bf16 h[4]; uint2 u; } p;
        p.h[0] = (__bf16)f.x; p.h[1] = (__bf16)f.y;
        p.h[2] = (__bf16)f.z; p.h[3] = (__bf16)f.w;
        *(uint2*)(shm + off) = p.u;
    }
    __syncthreads();

    for (int ks = 0; ks < 16; ++ks) {
        const int cur = ks & 1;
        u16* Ab = shm + cur * 4096;
        u16* Bb = shm + 8192 + cur * 4096;
        if (ks < 15) {
            const int k1 = (ks + 1) * 32;
#pragma unroll
            for (int i = 0; i < 4; ++i)
                nA[i] = *(const float4*)(X + (size_t)(lr0 + srow[i]) * DIM + k1 + sc * 4);
#pragma unroll
            for (int i = 0; i < 2; ++i) {
                int idx = i * 256 + t, row = idx >> 2, ch = idx & 3;
                gload16(BT + (size_t)(c0 + row) * DIM + k1 + ch * 8,
                        shm + 8192 + (cur ^ 1) * 4096 + idx * 8);
            }
        }
        bf16x8 af[4], bfr[4];
#pragma unroll
        for (int mi = 0; mi < 4; ++mi) {
            int rl = wr * 64 + mi * 16 + cl;
            af[mi] = *(const bf16x8*)(Ab + rl * 32 + (q ^ ((rl >> 1) & 3)) * 8);
        }
#pragma unroll
        for (int ni = 0; ni < 4; ++ni)
            bfr[ni] = *(const bf16x8*)(Bb + (wc * 64 + ni * 16 + cl) * 32 + q * 8);
#pragma unroll
        for (int mi = 0; mi < 4; ++mi)
#pragma unroll
            for (int ni = 0; ni < 4; ++ni)
                acc[mi][ni] = __builtin_amdgcn_mfma_f32_16x16x32_bf16(af[mi], bfr[ni],
                                                                      acc[mi][ni], 0, 0, 0);
        if (ks < 15) {
            u16* An = shm + (cur ^ 1) * 4096;
#pragma unroll
            for (int i = 0; i < 4; ++i) {
                float4 f = nA[i];
                s1[i] += (f.x + f.y) + (f.z + f.w);
                s2[i] += f.x * f.x + f.y * f.y + f.z * f.z + f.w * f.w;
                int row = srow[i];
                int off = row * 32 +
                          (((((sc >> 1) ^ ((row >> 1) & 3)) << 1) | (sc & 1)) << 2);
                union { __bf16 h[4]; uint2 u; } p;
                p.h[0] = (__bf16)f.x; p.h[1] = (__bf16)f.y;
                p.h[2] = (__bf16)f.z; p.h[3] = (__bf16)f.w;
                *(uint2*)(An + off) = p.u;
            }
        }
        __syncthreads();
    }

    // ---- per-row LN stats: reduce across the 8 lanes sharing each row
#pragma unroll
    for (int i = 0; i < 4; ++i) {
        float a = s1[i], b2 = s2[i];
        a += __shfl_xor(a, 1, 64); a += __shfl_xor(a, 2, 64); a += __shfl_xor(a, 4, 64);
        b2 += __shfl_xor(b2, 1, 64); b2 += __shfl_xor(b2, 2, 64); b2 += __shfl_xor(b2, 4, 64);
        if (sc == 0) {
            int row = srow[i];
            float mu = a * (1.f / DIM);
            float var = b2 * (1.f / DIM) - mu * mu;
            muL[row] = mu;
            rsL[row] = rsqrtf(var + 1e-5f);
        }
    }
    __syncthreads();

    // ---- LN correction in-place on accumulators: F = rstd*(acc - mu*cs) + bW
    {
        float csv[4], bwv[4];
#pragma unroll
        for (int ni = 0; ni < 4; ++ni) {
            int col = c0 + wc * 64 + ni * 16 + cl;
            csv[ni] = cs[col]; bwv[ni] = bW[col];
        }
#pragma unroll
        for (int mi = 0; mi < 4; ++mi)
#pragma unroll
            for (int r = 0; r < 4; ++r) {
                int rl = wr * 64 + mi * 16 + q * 4 + r;
                float mu = muL[rl], rs = rsL[rl];
#pragma unroll
                for (int ni = 0; ni < 4; ++ni)
                    acc[mi][ni][r] = rs * (acc[mi][ni][r] - mu * csv[ni]) + bwv[ni];
            }
    }

    const int b = (r0 >> 8) & 63, n0 = r0 & 255;

    if (tns == 0) {          // seq-major Fseq (q only)
#pragma unroll
        for (int mi = 0; mi < 4; ++mi) {
            int lrow = wr * 64 + mi * 16 + q * 4;
#pragma unroll
            for (int ni = 0; ni < 4; ++ni) {
                int lcol = wc * 64 + ni * 16 + cl;
#pragma unroll
                for (int r = 0; r < 4; ++r)
                    Ct[(lrow + r) * 136 + lcol] = f2bf(acc[mi][ni][r]);
            }
        }
        __syncthreads();
#pragma unroll
        for (int i = 0; i < 8; ++i) {
            int idx = t + 256 * i, row = idx >> 4, ch = idx & 15;
            *(uint4*)(Fseq + (size_t)(lr0 + row) * DIM + c0 + ch * 8) =
                *(const uint4*)(Ct + row * 136 + ch * 8);
        }
        __syncthreads();
    }
    // transposed tile -> dim-major FT (n contiguous, full-line stores)
#pragma unroll
    for (int mi = 0; mi < 4; ++mi) {
        int lrow = wr * 64 + mi * 16 + q * 4;
#pragma unroll
        for (int ni = 0; ni < 4; ++ni) {
            int lcol = wc * 64 + ni * 16 + cl;
#pragma unroll
            for (int r = 0; r < 4; ++r)
                Ct[lcol * 136 + lrow + r] = f2bf(acc[mi][ni][r]);
        }
    }
    __syncthreads();
#pragma unroll
    for (int i = 0; i < 8; ++i) {
        int idx = t + 256 * i, lc = idx >> 4, ch = idx & 15;
        *(uint4*)(FT + (((size_t)(tns * 64 + b) * 512 + c0 + lc) * 256 + n0 + ch * 8)) =
            *(const uint4*)(Ct + lc * 136 + ch * 8);
    }
}

// ---------------------------------------------------------------------------
// Kernel 3: per-(hb, tns) stats via MFMA Gram.
// ---------------------------------------------------------------------------
__global__ __launch_bounds__(256)
void stats_kernel(const u16* __restrict__ FT, float* __restrict__ norms,
                  float2* __restrict__ vc)
{
    __shared__ u16 ET[64 * 264];
    __shared__ float mu[64];
    __shared__ float red[4][64];
    __shared__ float wr3[4][3];
    const int hb = blockIdx.x, tns = blockIdx.y, h = hb >> 6, b = hb & 63;
    const int t = threadIdx.x, lane = t & 63, w = t >> 6, cl = lane & 15, q = lane >> 4;
    const size_t Fb = ((size_t)(tns * 64 + b) * 512 + h * 64) * 256;

#pragma unroll
    for (int i = 0; i < 8; ++i) {
        int idx = t + 256 * i;
        int row = idx >> 5, ch = idx & 31;
        *(bf16x8*)(ET + row * 264 + ch * 8) =
            *(const bf16x8*)(FT + Fb + (size_t)row * 256 + ch * 8);
    }
    __syncthreads();

    {
        float s = 0.f;
#pragma unroll
        for (int d = 0; d < 64; ++d) {
            float x = (float)*(const __bf16*)(ET + d * 264 + t);
            s += x * x;
        }
        norms[((size_t)tns * HB + hb) * 256 + t] = sqrtf(s);
    }
    {
        int d = t & 63, part = t >> 6;
        float s = 0.f;
#pragma unroll
        for (int i = 0; i < 8; ++i) {
            bf16x8 v8 = *(const bf16x8*)(ET + d * 264 + part * 64 + i * 8);
#pragma unroll
            for (int j = 0; j < 8; ++j) s += (float)v8[j];
        }
        red[part][d] = s;
    }
    __syncthreads();
    if (t < 64) mu[t] = (red[0][t] + red[1][t] + red[2][t] + red[3][t]) * (1.f / 256.f);
    __syncthreads();

    f32x4 g[4];
#pragma unroll
    for (int nj = 0; nj < 4; ++nj) g[nj] = (f32x4){0.f, 0.f, 0.f, 0.f};
#pragma unroll
    for (int ks = 0; ks < 8; ++ks) {
        bf16x8 af = *(const bf16x8*)(ET + (16 * w + cl) * 264 + ks * 32 + q * 8);
#pragma unroll
        for (int nj = 0; nj < 4; ++nj) {
            bf16x8 bfr = *(const bf16x8*)(ET + (16 * nj + cl) * 264 + ks * 32 + q * 8);
            g[nj] = __builtin_amdgcn_mfma_f32_16x16x32_bf16(af, bfr, g[nj], 0, 0, 0);
        }
    }
    float t2 = 0.f, d2 = 0.f, vs = 0.f;
#pragma unroll
    for (int nj = 0; nj < 4; ++nj) {
        int j = 16 * nj + cl;
        float mj = mu[j];
#pragma unroll
        for (int r = 0; r < 4; ++r) {
            int i = 16 * w + 4 * q + r;
            float gc = (g[nj][r] - 256.f * mu[i] * mj) * (1.f / 255.f);
            float g2 = gc * gc;
            t2 += g2;
            if (i == j) {
                d2 += g2;
                float sig = sqrtf(gc + 1e-8f);
                vs += fmaxf(1.f - sig, 0.f);
            }
        }
    }
#pragma unroll
    for (int o = 32; o > 0; o >>= 1) {
        t2 += __shfl_xor(t2, o, 64);
        d2 += __shfl_xor(d2, o, 64);
        vs += __shfl_xor(vs, o, 64);
    }
    if (lane == 0) { wr3[w][0] = t2; wr3[w][1] = d2; wr3[w][2] = vs; }
    __syncthreads();
    if (t == 0) {
        float T = 0.f, D = 0.f, V = 0.f;
        for (int i = 0; i < 4; ++i) { T += wr3[i][0]; D += wr3[i][1]; V += wr3[i][2]; }
        vc[(size_t)tns * HB + hb] = make_float2(V * (1.f / 64.f), (T - D) * (1.f / 64.f));
    }
}

// ---------------------------------------------------------------------------
// Kernel 4: attention per (h,b) via MFMA; chunk-combine folded in.
// ---------------------------------------------------------------------------
__global__ __launch_bounds__(256)
void attn_kernel(const u16* __restrict__ FT, const u16* __restrict__ Fseq,
                 const float* __restrict__ norms, const float2* __restrict__ vc,
                 const float* __restrict__ cov_logit, const float* __restrict__ var_logit,
                 u16* __restrict__ G)
{
    __shared__ u16 pool[256 * 72];
    __shared__ u16 MT[64 * 72];
    __shared__ float invq[256], invk[256], sv[64];
    const int hb = blockIdx.x, h = hb >> 6, b = hb & 63;
    const int t = threadIdx.x, lane = t & 63, w = t >> 6, cl = lane & 15, q = lane >> 4;
    u16* KT = pool;
    u16* VT = pool + 64 * 136;

    const float cw = sigmoidf_(*cov_logit), vw = sigmoidf_(*var_logit);
    const float cosw = 1.f - cw - vw;
    float s_hb;
    {
        int basec = hb & ~7;
        float vq = 0, cq = 0, vk = 0, ck = 0;
#pragma unroll
        for (int m = 0; m < 8; ++m) {
            float2 a = vc[basec + m];       vq += a.x; cq += a.y;
            float2 bb = vc[HB + basec + m]; vk += bb.x; ck += bb.y;
        }
        s_hb = (cw * cq * ck + vw * vq * vk) * (1.f / 64.f);
    }

    invq[t] = 1.f / norms[((size_t)0 * HB + hb) * 256 + t];
    invk[t] = 1.f / norms[((size_t)1 * HB + hb) * 256 + t];
    __syncthreads();

    const size_t FTk = ((size_t)(1 * 64 + b) * 512 + h * 64) * 256;
    const size_t FTv = ((size_t)(2 * 64 + b) * 512 + h * 64) * 256;
    f32x4 acc1[4];
#pragma unroll
    for (int nj = 0; nj < 4; ++nj) acc1[nj] = (f32x4){0.f, 0.f, 0.f, 0.f};
    float sp[4] = {0.f, 0.f, 0.f, 0.f};

    for (int c = 0; c < 2; ++c) {
#pragma unroll
        for (int i = 0; i < 4; ++i) {
            int idx = t + 256 * i;
            int row = idx >> 4, ch = idx & 15;
            int n0 = c * 128 + ch * 8;
            bf16x8 kv = *(const bf16x8*)(FT + FTk + (size_t)row * 256 + n0);
            bf16x8 vv = *(const bf16x8*)(FT + FTv + (size_t)row * 256 + n0);
            bf16x8 ksc;
#pragma unroll
            for (int j = 0; j < 8; ++j) ksc[j] = (__bf16)((float)kv[j] * invk[n0 + j]);
            *(bf16x8*)(KT + row * 136 + ch * 8) = ksc;
            *(bf16x8*)(VT + row * 136 + ch * 8) = vv;
        }
        __syncthreads();
#pragma unroll
        for (int ks = 0; ks < 4; ++ks) {
            bf16x8 af = *(const bf16x8*)(KT + (16 * w + cl) * 136 + ks * 32 + q * 8);
#pragma unroll
            for (int nj = 0; nj < 4; ++nj) {
                bf16x8 bfr = *(const bf16x8*)(VT + (16 * nj + cl) * 136 + ks * 32 + q * 8);
                if (w == 0) {
                    float s = 0.f;
#pragma unroll
                    for (int j = 0; j < 8; ++j) s += (float)bfr[j];
                    sp[nj] += s;
                }
                acc1[nj] = __builtin_amdgcn_mfma_f32_16x16x32_bf16(af, bfr, acc1[nj], 0, 0, 0);
            }
        }
        __syncthreads();
    }
    if (w == 0) {
#pragma unroll
        for (int nj = 0; nj < 4; ++nj) {
            float s = sp[nj];
            s += __shfl_xor(s, 16, 64);
            s += __shfl_xor(s, 32, 64);
            if (q == 0) sv[16 * nj + cl] = s;
        }
    }
#pragma unroll
    for (int nj = 0; nj < 4; ++nj)
#pragma unroll
        for (int r = 0; r < 4; ++r)
            MT[(16 * nj + cl) * 72 + 16 * w + 4 * q + r] = f2bf(acc1[nj][r]);
    __syncthreads();

    f32x4 acc2[4][4];
#pragma unroll
    for (int mi = 0; mi < 4; ++mi)
#pragma unroll
        for (int nj = 0; nj < 4; ++nj) acc2[mi][nj] = (f32x4){0.f, 0.f, 0.f, 0.f};
    const size_t Fq = (size_t)(b * 256) * DIM + h * 64;
#pragma unroll
    for (int ks2 = 0; ks2 < 2; ++ks2) {
        bf16x8 bfm[4];
#pragma unroll
        for (int nj = 0; nj < 4; ++nj)
            bfm[nj] = *(const bf16x8*)(MT + (16 * nj + cl) * 72 + ks2 * 32 + q * 8);
#pragma unroll
        for (int mi = 0; mi < 4; ++mi) {
            bf16x8 aq = *(const bf16x8*)(Fseq + Fq +
                         (size_t)(64 * w + 16 * mi + cl) * DIM + ks2 * 32 + q * 8);
#pragma unroll
            for (int nj = 0; nj < 4; ++nj)
                acc2[mi][nj] = __builtin_amdgcn_mfma_f32_16x16x32_bf16(aq, bfm[nj],
                                                                       acc2[mi][nj], 0, 0, 0);
        }
    }
    __syncthreads();
    u16* Os = pool;
#pragma unroll
    for (int mi = 0; mi < 4; ++mi) {
        int nbase = 64 * w + 16 * mi + 4 * q;
#pragma unroll
        for (int nj = 0; nj < 4; ++nj) {
            int j = 16 * nj + cl;
            float svj = sv[j];
#pragma unroll
            for (int r = 0; r < 4; ++r) {
                float o = cosw * acc2[mi][nj][r] * invq[nbase + r] + s_hb * svj;
                Os[(nbase + r) * 72 + j] = f2bf(o);
            }
        }
    }
    __syncthreads();
#pragma unroll
    for (int i = 0; i < 8; ++i) {
        int cidx = t + 256 * i;
        int row = cidx >> 3, ch = cidx & 7;
        *(uint4*)(G + (size_t)(b * 256 + row) * DIM + h * 64 + ch * 8) =
            *(const uint4*)(Os + row * 72 + ch * 8);
    }
}

// ---------------------------------------------------------------------------
// Kernel 5: out GEMM  out[M,512] = G[M,512] @ W_out^T + b_out (fp32 out)
// XCD-aware remap like in_gemm.
// ---------------------------------------------------------------------------
__global__ __launch_bounds__(256)
void out_gemm_kernel(const u16* __restrict__ A, const u16* __restrict__ BT,
                     const float* __restrict__ bias, float* __restrict__ C)
{
    __shared__ u16 As[128 * 32];
    __shared__ u16 Bs[128 * 32];
    const int t = threadIdx.x, lane = t & 63, w = t >> 6;
    const int wr = w >> 1, wc = w & 1;
    const int flat = blockIdx.y * 4 + blockIdx.x;   // grid (4, 128), 512 blocks
    const int rt = (flat & 7) * 16 + ((flat >> 3) >> 2);
    const int c0 = ((flat >> 3) & 3) * 128;
    const int r0 = rt * 128;
    const int cl = lane & 15, q = lane >> 4;

    f32x4 acc[4][4];
#pragma unroll
    for (int i = 0; i < 4; ++i)
#pragma unroll
        for (int j = 0; j < 4; ++j) acc[i][j] = (f32x4){0.f, 0.f, 0.f, 0.f};

    for (int k0 = 0; k0 < DIM; k0 += 32) {
#pragma unroll
        for (int i = 0; i < 2; ++i) {
            int idx = i * 256 + t;
            int row = idx >> 2, ch = idx & 3;
            gload16(A  + (size_t)(r0 + row) * DIM + k0 + ch * 8, As + idx * 8);
            gload16(BT + (size_t)(c0 + row) * DIM + k0 + ch * 8, Bs + idx * 8);
        }
        __syncthreads();
        bf16x8 af[4], bfr[4];
#pragma unroll
        for (int mi = 0; mi < 4; ++mi)
            af[mi] = *(const bf16x8*)(As + (wr * 64 + mi * 16 + cl) * 32 + q * 8);
#pragma unroll
        for (int ni = 0; ni < 4; ++ni)
            bfr[ni] = *(const bf16x8*)(Bs + (wc * 64 + ni * 16 + cl) * 32 + q * 8);
#pragma unroll
        for (int mi = 0; mi < 4; ++mi)
#pragma unroll
            for (int ni = 0; ni < 4; ++ni)
                acc[mi][ni] = __builtin_amdgcn_mfma_f32_16x16x32_bf16(af[mi], bfr[ni],
                                                                      acc[mi][ni], 0, 0, 0);
        __syncthreads();
    }
#pragma unroll
    for (int mi = 0; mi < 4; ++mi) {
        int row0 = r0 + wr * 64 + mi * 16 + q * 4;
#pragma unroll
        for (int ni = 0; ni < 4; ++ni) {
            int col = c0 + wc * 64 + ni * 16 + cl;
            float bv = bias[col];
#pragma unroll
            for (int r = 0; r < 4; ++r)
                C[(size_t)(row0 + r) * DIM + col] = acc[mi][ni][r] + bv;
        }
    }
}

// ---------------------------------------------------------------------------
extern "C" void kernel_launch(void* const* d_in, const int* in_sizes, int n_in,
                              void* d_out, int out_size, void* d_ws, size_t ws_size,
                              hipStream_t stream)
{
    const float* q         = (const float*)d_in[0];
    const float* k         = (const float*)d_in[1];
    const float* v         = (const float*)d_in[2];
    const float* ln_g      = (const float*)d_in[3];
    const float* ln_b      = (const float*)d_in[4];
    const float* W_in      = (const float*)d_in[5];
    const float* W_out     = (const float*)d_in[6];
    const float* b_out     = (const float*)d_in[7];
    const float* cov_logit = (const float*)d_in[8];
    const float* var_logit = (const float*)d_in[9];
    float* out = (float*)d_out;

    // workspace (~86 MB):
    char* base = (char*)d_ws;
    u16*    FT    = (u16*)base;                          // 50,331,648
    u16*    Fseq  = (u16*)(base + 50331648);             // 16,777,216
    u16*    Gb    = (u16*)(base + 67108864);             // 16,777,216
    u16*    WT    = (u16*)(base + 83886080);             //  1,048,576
    float*  norms = (float*)(base + 84934656);           //  1,048,576
    float2* vc    = (float2*)(base + 85983232);          //      8,192
    float*  cs    = (float*)(base + 85991424);           //      2,048
    float*  bW    = cs + 512;                            //      2,048

    hipMemsetAsync(cs, 0, 4096, stream);   // zero cs + bW before atomic accumulation
    transpose_cast_kernel<<<dim3(8, 8, 2), 256, 0, stream>>>(W_in, W_out, ln_g, ln_b,
                                                             WT, cs, bW);
    in_gemm_kernel<<<dim3(4, 3 * NROWS / 128), 256, 0, stream>>>(q, k, v, WT, cs, bW,
                                                                 FT, Fseq);
    stats_kernel<<<dim3(HB, 2), 256, 0, stream>>>(FT, norms, vc);
    attn_kernel<<<dim3(HB), 256, 0, stream>>>(FT, Fseq, norms, vc,
                                              cov_logit, var_logit, Gb);
    out_gemm_kernel<<<dim3(4, NROWS / 128), 256, 0, stream>>>(
        Gb, WT + 512 * 512, b_out, out);
}

// Round 3
// 243.133 us; speedup vs baseline: 1.2748x; 1.2748x over previous
//
#include <hip/hip_runtime.h>
#include <cstdint>
#include <cstddef>

#define DIM    512
#define HEADS  8
#define DHEAD  64
#define NSEQ   256
#define BATCH  64
#define NROWS  (BATCH * NSEQ)   // 16384
#define HB     (HEADS * BATCH)  // 512

typedef unsigned short u16;
typedef __bf16 bf16x8 __attribute__((ext_vector_type(8)));
typedef float  f32x4  __attribute__((ext_vector_type(4)));

__device__ __forceinline__ float sigmoidf_(float x) { return 1.0f / (1.0f + expf(-x)); }

__device__ __forceinline__ u16 f2bf(float f) {
    union { float f; unsigned u; } a; a.f = f;
    return (u16)((a.u + 0x7fffu + ((a.u >> 16) & 1u)) >> 16);   // RNE
}

__device__ __forceinline__ void gload16(const void* g, void* l) {
    __builtin_amdgcn_global_load_lds((const __attribute__((address_space(1))) void*)g,
                                     (__attribute__((address_space(3))) void*)l, 16, 0, 0);
}

// ---------------------------------------------------------------------------
// Kernel 1: both weight transposes in one launch. z=0: W_in, z=1: W_out.
// ---------------------------------------------------------------------------
__global__ __launch_bounds__(256)
void transpose_cast_kernel(const float* __restrict__ W0, const float* __restrict__ W1,
                           u16* __restrict__ WT)
{
    __shared__ float tile[64][65];
    const int t = threadIdx.x;
    const int bx = blockIdx.x * 64, by = blockIdx.y * 64;
    const float* W = blockIdx.z ? W1 : W0;
    u16* dst = WT + (size_t)blockIdx.z * 512 * 512;
#pragma unroll
    for (int i = 0; i < 16; ++i) {
        int idx = i * 256 + t, r = idx >> 6, c = idx & 63;
        tile[r][c] = W[(size_t)(by + r) * DIM + bx + c];
    }
    __syncthreads();
#pragma unroll
    for (int i = 0; i < 16; ++i) {
        int idx = i * 256 + t, r = idx >> 6, c = idx & 63;
        dst[(size_t)(bx + r) * DIM + by + c] = f2bf(tile[c][r]);
    }
}

// ---------------------------------------------------------------------------
// Kernel 2: fused LayerNorm + bf16 cast for all of q|k|v in ONE launch.
// One wave per row; rows [0,49152). Output Abf is the GEMM A operand.
// ---------------------------------------------------------------------------
__global__ __launch_bounds__(256)
void ln_cast_kernel(const float* __restrict__ qp, const float* __restrict__ kp,
                    const float* __restrict__ vp, const float* __restrict__ gam,
                    const float* __restrict__ bet, u16* __restrict__ out)
{
    const int wid = threadIdx.x >> 6, lane = threadIdx.x & 63;
    const int row = blockIdx.x * 4 + wid;
    const int tns = row >> 14, lr = row & 16383;
    const float* X = (tns == 0) ? qp : (tns == 1) ? kp : vp;
    const float* xr = X + (size_t)lr * DIM;
    float4 a = *(const float4*)(xr + lane * 8);
    float4 b = *(const float4*)(xr + lane * 8 + 4);
    float v[8] = {a.x, a.y, a.z, a.w, b.x, b.y, b.z, b.w};
    float s = 0.f;
#pragma unroll
    for (int i = 0; i < 8; ++i) s += v[i];
#pragma unroll
    for (int o = 32; o > 0; o >>= 1) s += __shfl_xor(s, o, 64);
    const float mu = s * (1.f / DIM);
    float sq = 0.f;
#pragma unroll
    for (int i = 0; i < 8; ++i) { float d = v[i] - mu; sq += d * d; }
#pragma unroll
    for (int o = 32; o > 0; o >>= 1) sq += __shfl_xor(sq, o, 64);
    const float rstd = rsqrtf(sq * (1.f / DIM) + 1e-5f);
    float4 g0 = *(const float4*)(gam + lane * 8), g1 = *(const float4*)(gam + lane * 8 + 4);
    float4 b0 = *(const float4*)(bet + lane * 8), b1 = *(const float4*)(bet + lane * 8 + 4);
    float gv[8] = {g0.x, g0.y, g0.z, g0.w, g1.x, g1.y, g1.z, g1.w};
    float bv[8] = {b0.x, b0.y, b0.z, b0.w, b1.x, b1.y, b1.z, b1.w};
    union { u16 h[8]; uint4 u; } o16;
#pragma unroll
    for (int i = 0; i < 8; ++i) o16.h[i] = f2bf((v[i] - mu) * rstd * gv[i] + bv[i]);
    *(uint4*)(out + (size_t)row * DIM + lane * 8) = o16.u;
}

// ---------------------------------------------------------------------------
// Kernel 3: batched input GEMM (m97 structure).
// XCD-aware remap (T1): dispatch id flat -> XCD = flat&7 (round-robin);
// give each XCD the 4 col-blocks of the same A row-tile consecutively so the
// 128KB A row-tile stays in that XCD's L2.
// Epilogue: LDS bounce (union'd over As/Bs) -> coalesced Fseq (q) + FT stores.
// ---------------------------------------------------------------------------
__global__ __launch_bounds__(256)
void in_gemm_kernel(const u16* __restrict__ A, const u16* __restrict__ BT,
                    u16* __restrict__ FT, u16* __restrict__ Fseq)
{
    __shared__ u16 shm[128 * 136];        // union: {As[4096] | Bs[4096]} / Ct[17408]
    u16* As = shm;
    u16* Bs = shm + 4096;
    u16* Ct = shm;
    const int t = threadIdx.x, lane = t & 63, w = t >> 6;
    const int wr = w >> 1, wc = w & 1;
    // flat dispatch id (x fastest). XCD x gets flats {x, x+8, ...}; within an
    // XCD, consecutive flats walk col-blocks of one row-tile first.
    const int flat = blockIdx.y * 4 + blockIdx.x;          // 0..1535
    const int rt = (flat & 7) * 48 + ((flat >> 3) >> 2);   // 0..383
    const int c0 = ((flat >> 3) & 3) * 128;
    const int r0 = rt * 128;
    const int cl = lane & 15, q = lane >> 4;

    f32x4 acc[4][4];
#pragma unroll
    for (int i = 0; i < 4; ++i)
#pragma unroll
        for (int j = 0; j < 4; ++j) acc[i][j] = (f32x4){0.f, 0.f, 0.f, 0.f};

    for (int k0 = 0; k0 < DIM; k0 += 32) {
#pragma unroll
        for (int i = 0; i < 2; ++i) {
            int idx = i * 256 + t;
            int row = idx >> 2, ch = idx & 3;
            gload16(A  + (size_t)(r0 + row) * DIM + k0 + ch * 8, As + idx * 8);
            gload16(BT + (size_t)(c0 + row) * DIM + k0 + ch * 8, Bs + idx * 8);
        }
        __syncthreads();
        bf16x8 af[4], bfr[4];
#pragma unroll
        for (int mi = 0; mi < 4; ++mi)
            af[mi] = *(const bf16x8*)(As + (wr * 64 + mi * 16 + cl) * 32 + q * 8);
#pragma unroll
        for (int ni = 0; ni < 4; ++ni)
            bfr[ni] = *(const bf16x8*)(Bs + (wc * 64 + ni * 16 + cl) * 32 + q * 8);
#pragma unroll
        for (int mi = 0; mi < 4; ++mi)
#pragma unroll
            for (int ni = 0; ni < 4; ++ni)
                acc[mi][ni] = __builtin_amdgcn_mfma_f32_16x16x32_bf16(af[mi], bfr[ni],
                                                                      acc[mi][ni], 0, 0, 0);
        __syncthreads();
    }

    const int tns = r0 >> 14, b = (r0 >> 8) & 63, n0 = r0 & 255;
    const int lr0 = r0 & 16383;

    if (tns == 0) {          // seq-major Fseq (q only)
#pragma unroll
        for (int mi = 0; mi < 4; ++mi) {
            int lrow = wr * 64 + mi * 16 + q * 4;
#pragma unroll
            for (int ni = 0; ni < 4; ++ni) {
                int lcol = wc * 64 + ni * 16 + cl;
#pragma unroll
                for (int r = 0; r < 4; ++r)
                    Ct[(lrow + r) * 136 + lcol] = f2bf(acc[mi][ni][r]);
            }
        }
        __syncthreads();
#pragma unroll
        for (int i = 0; i < 8; ++i) {
            int idx = t + 256 * i, row = idx >> 4, ch = idx & 15;
            *(uint4*)(Fseq + (size_t)(lr0 + row) * DIM + c0 + ch * 8) =
                *(const uint4*)(Ct + row * 136 + ch * 8);
        }
        __syncthreads();
    }
    // transposed tile -> dim-major FT (n contiguous, full-line stores)
#pragma unroll
    for (int mi = 0; mi < 4; ++mi) {
        int lrow = wr * 64 + mi * 16 + q * 4;
#pragma unroll
        for (int ni = 0; ni < 4; ++ni) {
            int lcol = wc * 64 + ni * 16 + cl;
#pragma unroll
            for (int r = 0; r < 4; ++r)
                Ct[lcol * 136 + lrow + r] = f2bf(acc[mi][ni][r]);
        }
    }
    __syncthreads();
#pragma unroll
    for (int i = 0; i < 8; ++i) {
        int idx = t + 256 * i, lc = idx >> 4, ch = idx & 15;
        *(uint4*)(FT + (((size_t)(tns * 64 + b) * 512 + c0 + lc) * 256 + n0 + ch * 8)) =
            *(const uint4*)(Ct + lc * 136 + ch * 8);
    }
}

// ---------------------------------------------------------------------------
// Kernel 4: per-(hb, tns) stats via MFMA Gram.
// ---------------------------------------------------------------------------
__global__ __launch_bounds__(256)
void stats_kernel(const u16* __restrict__ FT, float* __restrict__ norms,
                  float2* __restrict__ vc)
{
    __shared__ u16 ET[64 * 264];
    __shared__ float mu[64];
    __shared__ float red[4][64];
    __shared__ float wr3[4][3];
    const int hb = blockIdx.x, tns = blockIdx.y, h = hb >> 6, b = hb & 63;
    const int t = threadIdx.x, lane = t & 63, w = t >> 6, cl = lane & 15, q = lane >> 4;
    const size_t Fb = ((size_t)(tns * 64 + b) * 512 + h * 64) * 256;

#pragma unroll
    for (int i = 0; i < 8; ++i) {
        int idx = t + 256 * i;
        int row = idx >> 5, ch = idx & 31;
        *(bf16x8*)(ET + row * 264 + ch * 8) =
            *(const bf16x8*)(FT + Fb + (size_t)row * 256 + ch * 8);
    }
    __syncthreads();

    {
        float s = 0.f;
#pragma unroll
        for (int d = 0; d < 64; ++d) {
            float x = (float)*(const __bf16*)(ET + d * 264 + t);
            s += x * x;
        }
        norms[((size_t)tns * HB + hb) * 256 + t] = sqrtf(s);
    }
    {
        int d = t & 63, part = t >> 6;
        float s = 0.f;
#pragma unroll
        for (int i = 0; i < 8; ++i) {
            bf16x8 v8 = *(const bf16x8*)(ET + d * 264 + part * 64 + i * 8);
#pragma unroll
            for (int j = 0; j < 8; ++j) s += (float)v8[j];
        }
        red[part][d] = s;
    }
    __syncthreads();
    if (t < 64) mu[t] = (red[0][t] + red[1][t] + red[2][t] + red[3][t]) * (1.f / 256.f);
    __syncthreads();

    f32x4 g[4];
#pragma unroll
    for (int nj = 0; nj < 4; ++nj) g[nj] = (f32x4){0.f, 0.f, 0.f, 0.f};
#pragma unroll
    for (int ks = 0; ks < 8; ++ks) {
        bf16x8 af = *(const bf16x8*)(ET + (16 * w + cl) * 264 + ks * 32 + q * 8);
#pragma unroll
        for (int nj = 0; nj < 4; ++nj) {
            bf16x8 bfr = *(const bf16x8*)(ET + (16 * nj + cl) * 264 + ks * 32 + q * 8);
            g[nj] = __builtin_amdgcn_mfma_f32_16x16x32_bf16(af, bfr, g[nj], 0, 0, 0);
        }
    }
    float t2 = 0.f, d2 = 0.f, vs = 0.f;
#pragma unroll
    for (int nj = 0; nj < 4; ++nj) {
        int j = 16 * nj + cl;
        float mj = mu[j];
#pragma unroll
        for (int r = 0; r < 4; ++r) {
            int i = 16 * w + 4 * q + r;
            float gc = (g[nj][r] - 256.f * mu[i] * mj) * (1.f / 255.f);
            float g2 = gc * gc;
            t2 += g2;
            if (i == j) {
                d2 += g2;
                float sig = sqrtf(gc + 1e-8f);
                vs += fmaxf(1.f - sig, 0.f);
            }
        }
    }
#pragma unroll
    for (int o = 32; o > 0; o >>= 1) {
        t2 += __shfl_xor(t2, o, 64);
        d2 += __shfl_xor(d2, o, 64);
        vs += __shfl_xor(vs, o, 64);
    }
    if (lane == 0) { wr3[w][0] = t2; wr3[w][1] = d2; wr3[w][2] = vs; }
    __syncthreads();
    if (t == 0) {
        float T = 0.f, D = 0.f, V = 0.f;
        for (int i = 0; i < 4; ++i) { T += wr3[i][0]; D += wr3[i][1]; V += wr3[i][2]; }
        vc[(size_t)tns * HB + hb] = make_float2(V * (1.f / 64.f), (T - D) * (1.f / 64.f));
    }
}

// ---------------------------------------------------------------------------
// Kernel 5: attention per (h,b) via MFMA; chunk-combine folded in.
// ---------------------------------------------------------------------------
__global__ __launch_bounds__(256)
void attn_kernel(const u16* __restrict__ FT, const u16* __restrict__ Fseq,
                 const float* __restrict__ norms, const float2* __restrict__ vc,
                 const float* __restrict__ cov_logit, const float* __restrict__ var_logit,
                 u16* __restrict__ G)
{
    __shared__ u16 pool[256 * 72];
    __shared__ u16 MT[64 * 72];
    __shared__ float invq[256], invk[256], sv[64];
    const int hb = blockIdx.x, h = hb >> 6, b = hb & 63;
    const int t = threadIdx.x, lane = t & 63, w = t >> 6, cl = lane & 15, q = lane >> 4;
    u16* KT = pool;
    u16* VT = pool + 64 * 136;

    const float cw = sigmoidf_(*cov_logit), vw = sigmoidf_(*var_logit);
    const float cosw = 1.f - cw - vw;
    float s_hb;
    {
        int basec = hb & ~7;
        float vq = 0, cq = 0, vk = 0, ck = 0;
#pragma unroll
        for (int m = 0; m < 8; ++m) {
            float2 a = vc[basec + m];       vq += a.x; cq += a.y;
            float2 bb = vc[HB + basec + m]; vk += bb.x; ck += bb.y;
        }
        s_hb = (cw * cq * ck + vw * vq * vk) * (1.f / 64.f);
    }

    invq[t] = 1.f / norms[((size_t)0 * HB + hb) * 256 + t];
    invk[t] = 1.f / norms[((size_t)1 * HB + hb) * 256 + t];
    __syncthreads();

    const size_t FTk = ((size_t)(1 * 64 + b) * 512 + h * 64) * 256;
    const size_t FTv = ((size_t)(2 * 64 + b) * 512 + h * 64) * 256;
    f32x4 acc1[4];
#pragma unroll
    for (int nj = 0; nj < 4; ++nj) acc1[nj] = (f32x4){0.f, 0.f, 0.f, 0.f};
    float sp[4] = {0.f, 0.f, 0.f, 0.f};

    for (int c = 0; c < 2; ++c) {
#pragma unroll
        for (int i = 0; i < 4; ++i) {
            int idx = t + 256 * i;
            int row = idx >> 4, ch = idx & 15;
            int n0 = c * 128 + ch * 8;
            bf16x8 kv = *(const bf16x8*)(FT + FTk + (size_t)row * 256 + n0);
            bf16x8 vv = *(const bf16x8*)(FT + FTv + (size_t)row * 256 + n0);
            bf16x8 ksc;
#pragma unroll
            for (int j = 0; j < 8; ++j) ksc[j] = (__bf16)((float)kv[j] * invk[n0 + j]);
            *(bf16x8*)(KT + row * 136 + ch * 8) = ksc;
            *(bf16x8*)(VT + row * 136 + ch * 8) = vv;
        }
        __syncthreads();
#pragma unroll
        for (int ks = 0; ks < 4; ++ks) {
            bf16x8 af = *(const bf16x8*)(KT + (16 * w + cl) * 136 + ks * 32 + q * 8);
#pragma unroll
            for (int nj = 0; nj < 4; ++nj) {
                bf16x8 bfr = *(const bf16x8*)(VT + (16 * nj + cl) * 136 + ks * 32 + q * 8);
                if (w == 0) {
                    float s = 0.f;
#pragma unroll
                    for (int j = 0; j < 8; ++j) s += (float)bfr[j];
                    sp[nj] += s;
                }
                acc1[nj] = __builtin_amdgcn_mfma_f32_16x16x32_bf16(af, bfr, acc1[nj], 0, 0, 0);
            }
        }
        __syncthreads();
    }
    if (w == 0) {
#pragma unroll
        for (int nj = 0; nj < 4; ++nj) {
            float s = sp[nj];
            s += __shfl_xor(s, 16, 64);
            s += __shfl_xor(s, 32, 64);
            if (q == 0) sv[16 * nj + cl] = s;
        }
    }
#pragma unroll
    for (int nj = 0; nj < 4; ++nj)
#pragma unroll
        for (int r = 0; r < 4; ++r)
            MT[(16 * nj + cl) * 72 + 16 * w + 4 * q + r] = f2bf(acc1[nj][r]);
    __syncthreads();

    f32x4 acc2[4][4];
#pragma unroll
    for (int mi = 0; mi < 4; ++mi)
#pragma unroll
        for (int nj = 0; nj < 4; ++nj) acc2[mi][nj] = (f32x4){0.f, 0.f, 0.f, 0.f};
    const size_t Fq = (size_t)(b * 256) * DIM + h * 64;
#pragma unroll
    for (int ks2 = 0; ks2 < 2; ++ks2) {
        bf16x8 bfm[4];
#pragma unroll
        for (int nj = 0; nj < 4; ++nj)
            bfm[nj] = *(const bf16x8*)(MT + (16 * nj + cl) * 72 + ks2 * 32 + q * 8);
#pragma unroll
        for (int mi = 0; mi < 4; ++mi) {
            bf16x8 aq = *(const bf16x8*)(Fseq + Fq +
                         (size_t)(64 * w + 16 * mi + cl) * DIM + ks2 * 32 + q * 8);
#pragma unroll
            for (int nj = 0; nj < 4; ++nj)
                acc2[mi][nj] = __builtin_amdgcn_mfma_f32_16x16x32_bf16(aq, bfm[nj],
                                                                       acc2[mi][nj], 0, 0, 0);
        }
    }
    __syncthreads();
    u16* Os = pool;
#pragma unroll
    for (int mi = 0; mi < 4; ++mi) {
        int nbase = 64 * w + 16 * mi + 4 * q;
#pragma unroll
        for (int nj = 0; nj < 4; ++nj) {
            int j = 16 * nj + cl;
            float svj = sv[j];
#pragma unroll
            for (int r = 0; r < 4; ++r) {
                float o = cosw * acc2[mi][nj][r] * invq[nbase + r] + s_hb * svj;
                Os[(nbase + r) * 72 + j] = f2bf(o);
            }
        }
    }
    __syncthreads();
#pragma unroll
    for (int i = 0; i < 8; ++i) {
        int cidx = t + 256 * i;
        int row = cidx >> 3, ch = cidx & 7;
        *(uint4*)(G + (size_t)(b * 256 + row) * DIM + h * 64 + ch * 8) =
            *(const uint4*)(Os + row * 72 + ch * 8);
    }
}

// ---------------------------------------------------------------------------
// Kernel 6: out GEMM  out[M,512] = G[M,512] @ W_out^T + b_out (fp32 out)
// XCD-aware remap (T1) like in_gemm.
// ---------------------------------------------------------------------------
__global__ __launch_bounds__(256)
void out_gemm_kernel(const u16* __restrict__ A, const u16* __restrict__ BT,
                     const float* __restrict__ bias, float* __restrict__ C)
{
    __shared__ u16 As[128 * 32];
    __shared__ u16 Bs[128 * 32];
    const int t = threadIdx.x, lane = t & 63, w = t >> 6;
    const int wr = w >> 1, wc = w & 1;
    const int flat = blockIdx.y * 4 + blockIdx.x;          // 0..511
    const int rt = (flat & 7) * 16 + ((flat >> 3) >> 2);   // 0..127
    const int c0 = ((flat >> 3) & 3) * 128;
    const int r0 = rt * 128;
    const int cl = lane & 15, q = lane >> 4;

    f32x4 acc[4][4];
#pragma unroll
    for (int i = 0; i < 4; ++i)
#pragma unroll
        for (int j = 0; j < 4; ++j) acc[i][j] = (f32x4){0.f, 0.f, 0.f, 0.f};

    for (int k0 = 0; k0 < DIM; k0 += 32) {
#pragma unroll
        for (int i = 0; i < 2; ++i) {
            int idx = i * 256 + t;
            int row = idx >> 2, ch = idx & 3;
            gload16(A  + (size_t)(r0 + row) * DIM + k0 + ch * 8, As + idx * 8);
            gload16(BT + (size_t)(c0 + row) * DIM + k0 + ch * 8, Bs + idx * 8);
        }
        __syncthreads();
        bf16x8 af[4], bfr[4];
#pragma unroll
        for (int mi = 0; mi < 4; ++mi)
            af[mi] = *(const bf16x8*)(As + (wr * 64 + mi * 16 + cl) * 32 + q * 8);
#pragma unroll
        for (int ni = 0; ni < 4; ++ni)
            bfr[ni] = *(const bf16x8*)(Bs + (wc * 64 + ni * 16 + cl) * 32 + q * 8);
#pragma unroll
        for (int mi = 0; mi < 4; ++mi)
#pragma unroll
            for (int ni = 0; ni < 4; ++ni)
                acc[mi][ni] = __builtin_amdgcn_mfma_f32_16x16x32_bf16(af[mi], bfr[ni],
                                                                      acc[mi][ni], 0, 0, 0);
        __syncthreads();
    }
#pragma unroll
    for (int mi = 0; mi < 4; ++mi) {
        int row0 = r0 + wr * 64 + mi * 16 + q * 4;
#pragma unroll
        for (int ni = 0; ni < 4; ++ni) {
            int col = c0 + wc * 64 + ni * 16 + cl;
            float bv = bias[col];
#pragma unroll
            for (int r = 0; r < 4; ++r)
                C[(size_t)(row0 + r) * DIM + col] = acc[mi][ni][r] + bv;
        }
    }
}

// ---------------------------------------------------------------------------
extern "C" void kernel_launch(void* const* d_in, const int* in_sizes, int n_in,
                              void* d_out, int out_size, void* d_ws, size_t ws_size,
                              hipStream_t stream)
{
    const float* q         = (const float*)d_in[0];
    const float* k         = (const float*)d_in[1];
    const float* v         = (const float*)d_in[2];
    const float* ln_g      = (const float*)d_in[3];
    const float* ln_b      = (const float*)d_in[4];
    const float* W_in      = (const float*)d_in[5];
    const float* W_out     = (const float*)d_in[6];
    const float* b_out     = (const float*)d_in[7];
    const float* cov_logit = (const float*)d_in[8];
    const float* var_logit = (const float*)d_in[9];
    float* out = (float*)d_out;

    // workspace (~120 MB):
    char* base = (char*)d_ws;
    u16*    Abf   = (u16*)base;                                   // 50,331,648 (LN'd q|k|v)
    u16*    WT    = (u16*)(base + 50331648);                      //  1,048,576
    u16*    FT    = (u16*)(base + 51380224);                      // 50,331,648
    u16*    Fseq  = (u16*)(base + 101711872);                     // 16,777,216
    float*  norms = (float*)(base + 118489088);                   //  1,048,576
    float2* vc    = (float2*)(base + 119537664);                  //      8,192
    u16*    Gb    = Abf;                                          // alias: Abf dead post-GEMM

    transpose_cast_kernel<<<dim3(8, 8, 2), 256, 0, stream>>>(W_in, W_out, WT);
    ln_cast_kernel<<<dim3(3 * NROWS / 4), 256, 0, stream>>>(q, k, v, ln_g, ln_b, Abf);
    in_gemm_kernel<<<dim3(4, 3 * NROWS / 128), 256, 0, stream>>>(Abf, WT, FT, Fseq);
    stats_kernel<<<dim3(HB, 2), 256, 0, stream>>>(FT, norms, vc);
    attn_kernel<<<dim3(HB), 256, 0, stream>>>(FT, Fseq, norms, vc,
                                              cov_logit, var_logit, Gb);
    out_gemm_kernel<<<dim3(4, NROWS / 128), 256, 0, stream>>>(
        Gb, WT + 512 * 512, b_out, out);
}